// Round 4
// baseline (114.432 us; speedup 1.0000x reference)
//
#include <hip/hip_runtime.h>
#include <cstdint>
#include <cstddef>

// ---------------------------------------------------------------------------
// MultiHeadExternalAttention, algebraically collapsed:
//   logits = x @ Wk   (Wk[e,hm] = sum_d W_in[e,h*128+d]*W_mk[d,m]) + bk
//   attn   = softmax_n(logits); attn /= (sum_m attn + 1e-9)
//   out    = attn @ Wv (Wv[hm,e] = sum_d W_mv[m,d]*W_out[h*128+d,e]) + bv
// B=32 N=1024 E=512 H=16 M=16 HM=256 ROWS=32768
// Inputs fp32, output fp32. Internals bf16 via MFMA.
// Round 4: both GEMMs -> 8 waves/block, reg-prefetch + LDS dbuf + raw
// s_barrier (no vmcnt drain); gemm_b de-fused (p_prep materializes P once).
// ---------------------------------------------------------------------------

typedef unsigned short u16;
typedef unsigned int u32;
typedef short s16x8 __attribute__((ext_vector_type(8)));
typedef float f32x4 __attribute__((ext_vector_type(4)));

// workspace layout (bytes)
constexpr size_t OFF_BVP  = 0;                        // f32 [32][512] (64 KiB)
constexpr size_t OFF_WKT  = 1u << 20;                 // u16 [256][512]  (256 KiB)
constexpr size_t OFF_WVT  = OFF_WKT + (1u << 18);     // u16 [512][256]  (256 KiB)
constexpr size_t OFF_BK   = OFF_WVT + (1u << 18);     // f32 [256]
constexpr size_t OFF_BV   = OFF_BK + 4096;            // f32 [512]
constexpr size_t OFF_INV  = OFF_BV + 4096;            // f32 [32][256]
constexpr size_t OFF_PART = 2u << 20;                 // f32 [32][8][256]
constexpr size_t OFF_LOG  = 4u << 20;                 // u16 [32768][256] (16 MiB)
constexpr size_t OFF_P    = 20u << 20;                // u16 [32768][256] (16 MiB)

__device__ __forceinline__ float bf2f(u16 v) {
  union { u32 u; float f; } c; c.u = ((u32)v) << 16; return c.f;
}
__device__ __forceinline__ u16 f2bf(float f) {
  union { float f; u32 u; } c; c.f = f;
  u32 u = c.u;
  u += 0x7fffu + ((u >> 16) & 1u);
  return (u16)(u >> 16);
}
__device__ __forceinline__ uint4 pack_bf8(float4 lo, float4 hi) {
  return make_uint4((u32)f2bf(lo.x) | ((u32)f2bf(lo.y) << 16),
                    (u32)f2bf(lo.z) | ((u32)f2bf(lo.w) << 16),
                    (u32)f2bf(hi.x) | ((u32)f2bf(hi.y) << 16),
                    (u32)f2bf(hi.z) | ((u32)f2bf(hi.w) << 16));
}

__device__ __forceinline__ void mfma_bf16(f32x4& acc, s16x8 a, s16x8 b) {
  asm volatile("v_mfma_f32_16x16x32_bf16 %0, %1, %2, %0"
               : "+v"(acc) : "v"(a), "v"(b));
}

// raw barrier: LDS-drain + s_barrier, WITHOUT the vmcnt(0) drain that
// __syncthreads() emits — in-flight global prefetch loads survive it.
#define PIPE_BARRIER() asm volatile("s_waitcnt lgkmcnt(0)\n\ts_barrier" ::: "memory")

// ---------------------------------------------------------------------------
// WkT[hm][e] = sum_d W_in[e, h*128+d] * W_mk[d, m]   (stored transposed, bf16)
__global__ void prep_wkt(const float* __restrict__ wi, const float* __restrict__ wm,
                         u16* __restrict__ wkT) {
  const int gid = blockIdx.x * 256 + threadIdx.x;
  const int hm = gid & 255, e = gid >> 8;
  const int h = hm >> 4, m = hm & 15;
  float acc = 0.f;
  for (int d = 0; d < 128; d++)
    acc += wi[e * 2048 + h * 128 + d] * wm[d * 16 + m];
  wkT[hm * 512 + e] = f2bf(acc);
}

// WvT[e][hm] = sum_d W_mv[m,d] * W_out[h*128+d, e]   (stored transposed, bf16)
__global__ void prep_wvt(const float* __restrict__ mv, const float* __restrict__ wo,
                         u16* __restrict__ wvT) {
  const int gid = blockIdx.x * 256 + threadIdx.x;
  const int hm = gid & 255, e = gid >> 8;
  const int h = hm >> 4, m = hm & 15;
  float acc = 0.f;
  for (int d = 0; d < 128; d++)
    acc += mv[m * 128 + d] * wo[(h * 128 + d) * 512 + e];
  wvT[e * 256 + hm] = f2bf(acc);
}

// bk[hm] = b_mk[m] + sum_d b_in[h*128+d]*W_mk[d,m]
__global__ void prep_bk(const float* __restrict__ b_in, const float* __restrict__ wm,
                        const float* __restrict__ b_mk, float* __restrict__ bk) {
  const int t = threadIdx.x;
  const int h = t >> 4, m = t & 15;
  float acc = b_mk[m];
  for (int d = 0; d < 128; d++) acc += b_in[h * 128 + d] * wm[d * 16 + m];
  bk[t] = acc;
}

// bv partial: block k reduces 64 coalesced rows of W_out weighted by b_mv
__global__ void bv_part(const float* __restrict__ wo, const float* __restrict__ b_mv,
                        float* __restrict__ bvp) {
  const int k = blockIdx.x;   // 32
  const int t = threadIdx.x;  // 256
  float a0 = 0.f, a1 = 0.f;
  const int c0 = k * 64;
#pragma unroll 8
  for (int c = c0; c < c0 + 64; c++) {
    const float w = b_mv[c & 127];
    a0 += w * wo[(size_t)c * 512 + t];
    a1 += w * wo[(size_t)c * 512 + 256 + t];
  }
  bvp[k * 512 + t] = a0;
  bvp[k * 512 + 256 + t] = a1;
}

// bv[e] = b_out[e] + sum_k bvp[k][e]
__global__ void bv_fin(const float* __restrict__ bvp, const float* __restrict__ b_out,
                       float* __restrict__ bv) {
  const int e = blockIdx.x * 256 + threadIdx.x;  // 512
  float s = b_out[e];
#pragma unroll
  for (int k = 0; k < 32; k++) s += bvp[k * 512 + e];
  bv[e] = s;
}

// ---------------------------------------------------------------------------
// GEMM A: logits[32768,256] = x[32768,512](fp32, cvt in-reg) @ Wk + bk, bf16.
// 128x128 tile, BK=32, 8 waves (2r x 4c; each wave 64x32 = acc[4][2]).
// Reg-prefetch + LDS double-buffer + one raw barrier per K-iter.
// LDS cells [kg][row] of 8 bf16 (16 B) -> conflict-free ds_read_b128.
__global__ __launch_bounds__(512, 4) void gemm_a(const float* __restrict__ x,
                                                 const u16* __restrict__ wkT,
                                                 const float* __restrict__ bk,
                                                 u16* __restrict__ logits) {
  __shared__ u16 As[2][4096];  // 4 kg * 128 rows * 8
  __shared__ u16 Bs[2][4096];
  const int t = threadIdx.x;
  const int l = t & 63, w = t >> 6;
  const int wr = w >> 2, wc = w & 3;
  const int lrow = l & 15, lkg = l >> 4;
  const int gCol0 = blockIdx.x << 7;
  const int gRow0 = blockIdx.y << 7;
  const int srow = t & 127, skg = t >> 7;
  const int wIdx = (skg * 128 + srow) * 8;

  f32x4 acc[4][2];
#pragma unroll
  for (int i = 0; i < 4; i++)
#pragma unroll
    for (int n = 0; n < 2; n++) acc[i][n] = f32x4{0.f, 0.f, 0.f, 0.f};

  const float* aSrc = x + (size_t)(gRow0 + srow) * 512 + skg * 8;
  const u16* bSrc = wkT + (size_t)(gCol0 + srow) * 512 + skg * 8;

  float4 fa0, fa1;
  uint4 bReg;
  fa0 = *(const float4*)(aSrc);
  fa1 = *(const float4*)(aSrc + 4);
  bReg = *(const uint4*)(bSrc);

  for (int it = 0; it < 16; ++it) {
    const int buf = it & 1;
    // stage current chunk (compiler inserts vmcnt waits for fa/bReg)
    *(uint4*)&As[buf][wIdx] = pack_bf8(fa0, fa1);
    *(uint4*)&Bs[buf][wIdx] = bReg;
    // issue next chunk's loads — they stay in flight across the barrier
    if (it < 15) {
      const int k1 = (it + 1) * 32;
      fa0 = *(const float4*)(aSrc + k1);
      fa1 = *(const float4*)(aSrc + k1 + 4);
      bReg = *(const uint4*)(bSrc + k1);
    }
    PIPE_BARRIER();
    s16x8 af[4];
#pragma unroll
    for (int i = 0; i < 4; i++)
      af[i] = *(const s16x8*)&As[buf][(lkg * 128 + wr * 64 + i * 16 + lrow) * 8];
#pragma unroll
    for (int n = 0; n < 2; n++) {
      s16x8 bfr = *(const s16x8*)&Bs[buf][(lkg * 128 + wc * 32 + n * 16 + lrow) * 8];
#pragma unroll
      for (int i = 0; i < 4; i++) mfma_bf16(acc[i][n], af[i], bfr);
    }
  }
  asm volatile("s_nop 7\n\ts_nop 7");
  const int crow = (l >> 4) * 4;
#pragma unroll
  for (int n = 0; n < 2; n++) {
    const int col = gCol0 + wc * 32 + n * 16 + (l & 15);
    const float bias = bk[col];
#pragma unroll
    for (int i = 0; i < 4; i++) {
      const int row = gRow0 + wr * 64 + i * 16 + crow;
#pragma unroll
      for (int j = 0; j < 4; j++)
        logits[(size_t)(row + j) * 256 + col] = f2bf(acc[i][n][j] + bias);
    }
  }
}

// per-(b,hm) partial sum of exp over 128-row chunk (no max needed: |logit|<~3)
__global__ __launch_bounds__(256) void colsum_part(const u16* __restrict__ logits,
                                                   float* __restrict__ part) {
  const int b = blockIdx.x, ch = blockIdx.y, hm = threadIdx.x;
  const u16* p = logits + ((size_t)(b * 1024 + ch * 128) * 256) + hm;
  float s = 0.f;
#pragma unroll 4
  for (int n = 0; n < 128; n++) s += __expf(bf2f(p[(size_t)n * 256]));
  part[(b * 8 + ch) * 256 + hm] = s;
}

__global__ void colsum_fin(const float* __restrict__ part, float* __restrict__ inv) {
  const int b = blockIdx.x, hm = threadIdx.x;
  float s = 0.f;
#pragma unroll
  for (int c = 0; c < 8; c++) s += part[(b * 8 + c) * 256 + hm];
  inv[b * 256 + hm] = 1.0f / s;
}

// P[r][hm] = exp(lg)*inv, L1-normalized per (row, head). 16 threads per row.
__global__ __launch_bounds__(256) void p_prep(const u16* __restrict__ lg,
                                              const float* __restrict__ inv,
                                              u16* __restrict__ P) {
  const int t = threadIdx.x;
  const int r = blockIdx.x * 16 + (t >> 4);
  const int h = t & 15;
  const int b = r >> 10;
  const u16* src = lg + (size_t)r * 256 + h * 16;
  uint4 q0 = *(const uint4*)src;
  uint4 q1 = *(const uint4*)(src + 8);
  const float* ivp = inv + b * 256 + h * 16;
  const u32 qq[8] = {q0.x, q0.y, q0.z, q0.w, q1.x, q1.y, q1.z, q1.w};
  float e[16];
#pragma unroll
  for (int p = 0; p < 8; p++) {
    e[p * 2]     = __expf(bf2f((u16)(qq[p] & 0xffffu))) * ivp[p * 2];
    e[p * 2 + 1] = __expf(bf2f((u16)(qq[p] >> 16)))     * ivp[p * 2 + 1];
  }
  float s = 0.f;
#pragma unroll
  for (int p = 0; p < 16; p++) s += e[p];
  const float rs = 1.0f / (s + 1e-9f);
  u32 pk[8];
#pragma unroll
  for (int p = 0; p < 8; p++)
    pk[p] = (u32)f2bf(e[p * 2] * rs) | ((u32)f2bf(e[p * 2 + 1] * rs) << 16);
  u16* dst = P + (size_t)r * 256 + h * 16;
  *(uint4*)dst = make_uint4(pk[0], pk[1], pk[2], pk[3]);
  *(uint4*)(dst + 8) = make_uint4(pk[4], pk[5], pk[6], pk[7]);
}

// ---------------------------------------------------------------------------
// GEMM B: out[32768,512] = P[32768,256] @ Wv (via WvT) + bv (fp32 out).
// 128x256 tile, BK=32, 8 waves (2r x 4c; each wave 64x64 = acc[4][4]).
// Same pipeline structure as gemm_a.
__global__ __launch_bounds__(512, 4) void gemm_b(const u16* __restrict__ P,
                                                 const u16* __restrict__ wvT,
                                                 const float* __restrict__ bvv,
                                                 float* __restrict__ out) {
  __shared__ u16 As[2][4096];  // 4 kg * 128 rows * 8
  __shared__ u16 Bs[2][8192];  // 4 kg * 256 cols * 8
  const int t = threadIdx.x;
  const int l = t & 63, w = t >> 6;
  const int wr = w >> 2, wc = w & 3;
  const int lrow = l & 15, lkg = l >> 4;
  const int gCol0 = blockIdx.x << 8;
  const int gRow0 = blockIdx.y << 7;
  const int arow = t & 127, akg = t >> 7;
  const int aIdx = (akg * 128 + arow) * 8;
  const int bcol = t & 255, bkg = (t >> 8) * 2;
  const int bIdx0 = (bkg * 256 + bcol) * 8;
  const int bIdx1 = ((bkg + 1) * 256 + bcol) * 8;

  f32x4 acc[4][4];
#pragma unroll
  for (int i = 0; i < 4; i++)
#pragma unroll
    for (int n = 0; n < 4; n++) acc[i][n] = f32x4{0.f, 0.f, 0.f, 0.f};

  const u16* aSrc = P + (size_t)(gRow0 + arow) * 256 + akg * 8;
  const u16* bSrc = wvT + (size_t)(gCol0 + bcol) * 256 + bkg * 8;

  uint4 aReg, bR0, bR1;
  aReg = *(const uint4*)(aSrc);
  bR0 = *(const uint4*)(bSrc);
  bR1 = *(const uint4*)(bSrc + 8);

  for (int it = 0; it < 8; ++it) {
    const int buf = it & 1;
    *(uint4*)&As[buf][aIdx] = aReg;
    *(uint4*)&Bs[buf][bIdx0] = bR0;
    *(uint4*)&Bs[buf][bIdx1] = bR1;
    if (it < 7) {
      const int k1 = (it + 1) * 32;
      aReg = *(const uint4*)(aSrc + k1);
      bR0 = *(const uint4*)(bSrc + k1);
      bR1 = *(const uint4*)(bSrc + k1 + 8);
    }
    PIPE_BARRIER();
    s16x8 af[4];
#pragma unroll
    for (int i = 0; i < 4; i++)
      af[i] = *(const s16x8*)&As[buf][(lkg * 128 + wr * 64 + i * 16 + lrow) * 8];
#pragma unroll
    for (int n = 0; n < 4; n++) {
      s16x8 bfr = *(const s16x8*)&Bs[buf][(lkg * 256 + wc * 64 + n * 16 + lrow) * 8];
#pragma unroll
      for (int i = 0; i < 4; i++) mfma_bf16(acc[i][n], af[i], bfr);
    }
  }
  asm volatile("s_nop 7\n\ts_nop 7");
  const int crow = (l >> 4) * 4;
#pragma unroll
  for (int n = 0; n < 4; n++) {
    const int col = gCol0 + wc * 64 + n * 16 + (l & 15);
    const float bias = bvv[col];
#pragma unroll
    for (int i = 0; i < 4; i++) {
      const int row = gRow0 + wr * 64 + i * 16 + crow;
#pragma unroll
      for (int j = 0; j < 4; j++)
        out[(size_t)(row + j) * 512 + col] = acc[i][n][j] + bias;
    }
  }
}

// ---------------------------------------------------------------------------
extern "C" void kernel_launch(void* const* d_in, const int* in_sizes, int n_in,
                              void* d_out, int out_size, void* d_ws, size_t ws_size,
                              hipStream_t stream) {
  (void)in_sizes; (void)n_in; (void)out_size; (void)ws_size;
  const float* x     = (const float*)d_in[0];
  const float* W_in  = (const float*)d_in[1];
  const float* b_in  = (const float*)d_in[2];
  const float* W_mk  = (const float*)d_in[3];
  const float* b_mk  = (const float*)d_in[4];
  const float* W_mv  = (const float*)d_in[5];
  const float* b_mv  = (const float*)d_in[6];
  const float* W_out = (const float*)d_in[7];
  const float* b_out = (const float*)d_in[8];

  char* ws = (char*)d_ws;
  float* bvp  = (float*)(ws + OFF_BVP);
  u16*   wkT  = (u16*)(ws + OFF_WKT);
  u16*   wvT  = (u16*)(ws + OFF_WVT);
  float* bk   = (float*)(ws + OFF_BK);
  float* bv   = (float*)(ws + OFF_BV);
  float* inv  = (float*)(ws + OFF_INV);
  float* part = (float*)(ws + OFF_PART);
  u16*   lg   = (u16*)(ws + OFF_LOG);
  u16*   Pm   = (u16*)(ws + OFF_P);
  float* outp = (float*)d_out;

  prep_wkt<<<512, 256, 0, stream>>>(W_in, W_mk, wkT);
  prep_wvt<<<512, 256, 0, stream>>>(W_mv, W_out, wvT);
  prep_bk<<<1, 256, 0, stream>>>(b_in, W_mk, b_mk, bk);
  bv_part<<<32, 256, 0, stream>>>(W_out, b_mv, bvp);
  bv_fin<<<2, 256, 0, stream>>>(bvp, b_out, bv);
  gemm_a<<<dim3(2, 256), 512, 0, stream>>>(x, wkT, bk, lg);
  colsum_part<<<dim3(32, 8), 256, 0, stream>>>(lg, part);
  colsum_fin<<<32, 256, 0, stream>>>(part, inv);
  p_prep<<<2048, 256, 0, stream>>>(lg, inv, Pm);
  gemm_b<<<dim3(2, 256), 512, 0, stream>>>(Pm, wvT, bv, outp);
}